// Round 2
// baseline (279.348 us; speedup 1.0000x reference)
//
#include <hip/hip_runtime.h>

#define IMG_H 512
#define IMG_W 512
#define TILE  32
#define RAD   5
#define KS    11
#define SP_H  42          // TILE + 2*RAD halo rows
#define HT_W  44          // 42 rows padded to 44 for float4 LDS reads
#define NSLOT 64

__global__ __launch_bounds__(256, 5)
void ssim_main(const float* __restrict__ pred, const float* __restrict__ targ,
               double* __restrict__ acc)
{
    __shared__ float hT[5][TILE][HT_W];   // [quantity][out_col][halo_row]
    __shared__ float red[4];

    // normalized 11-tap Gaussian (sigma=1.5), precomputed
    const float wn[KS] = {0.00102838f, 0.00759876f, 0.03600077f, 0.10936069f,
                          0.21300554f, 0.26601173f, 0.21300554f, 0.10936069f,
                          0.03600077f, 0.00759876f, 0.00102838f};

    const int tid = threadIdx.x;
    const int tx = blockIdx.x, ty = blockIdx.y, img = blockIdx.z;
    const float* __restrict__ p = pred + (size_t)img * (IMG_H * IMG_W);
    const float* __restrict__ t = targ + (size_t)img * (IMG_H * IMG_W);
    const int gr0 = ty * TILE - RAD;          // first halo row (global)
    const int gcb = tx * TILE;                // first output col (global)
    const bool colsOK = (tx >= 1) && (tx <= 14);  // 20-float window fully in-image

    // ---- Horizontal 11-tap pass: global -> registers -> hT (transposed) ----
    // item space: 42 halo rows x 8 col-groups of 4 outputs = 336
    for (int i = tid; i < SP_H * 8; i += 256) {
        const int r  = i % SP_H;
        const int c0 = (i / SP_H) * 4;
        const int gr = gr0 + r;
        float hq[5][4];
        if (gr < 0 || gr >= IMG_H) {
            #pragma unroll
            for (int q = 0; q < 5; ++q)
                #pragma unroll
                for (int j = 0; j < 4; ++j) hq[q][j] = 0.f;
        } else {
            float pr[20], tr[20];
            const int cbase = gcb + c0 - 8;   // 16B-aligned when colsOK
            if (colsOK) {
                const float* rp = p + gr * IMG_W + cbase;
                const float* rt = t + gr * IMG_W + cbase;
                #pragma unroll
                for (int v = 0; v < 5; ++v) {
                    *(float4*)&pr[v * 4] = ((const float4*)rp)[v];
                    *(float4*)&tr[v * 4] = ((const float4*)rt)[v];
                }
            } else {
                #pragma unroll
                for (int e = 3; e < 17; ++e) {    // only indices 3..16 are used
                    int gc = cbase + e;
                    float pv = 0.f, tv = 0.f;
                    if (gc >= 0 && gc < IMG_W) {
                        pv = p[gr * IMG_W + gc];
                        tv = t[gr * IMG_W + gc];
                    }
                    pr[e] = pv; tr[e] = tv;
                }
            }
            #pragma unroll
            for (int j = 0; j < 4; ++j) {
                float sp = 0.f, st = 0.f, spp = 0.f, stt = 0.f, spt = 0.f;
                #pragma unroll
                for (int k = 0; k < KS; ++k) {
                    float pv = pr[j + k + 3], tv = tr[j + k + 3];
                    float w = wn[k];
                    float wp = w * pv, wt = w * tv;
                    sp += wp; st += wt;
                    spp = fmaf(wp, pv, spp);
                    stt = fmaf(wt, tv, stt);
                    spt = fmaf(wp, tv, spt);
                }
                hq[0][j] = sp; hq[1][j] = st; hq[2][j] = spp;
                hq[3][j] = stt; hq[4][j] = spt;
            }
        }
        #pragma unroll
        for (int q = 0; q < 5; ++q)
            #pragma unroll
            for (int j = 0; j < 4; ++j)
                hT[q][c0 + j][r] = hq[q][j];
    }
    __syncthreads();

    // ---- Vertical 11-tap pass (vectorized along transposed rows) + SSIM ----
    float lsum = 0.f;
    {
        const int c  = tid >> 3;          // output column 0..31
        const int r0 = (tid & 7) * 4;     // output row base 0..28
        float accv[5][4];
        #pragma unroll
        for (int q = 0; q < 5; ++q) {
            float h[16];
            #pragma unroll
            for (int v = 0; v < 4; ++v)
                *(float4*)&h[v * 4] = *(const float4*)&hT[q][c][r0 + v * 4];
            #pragma unroll
            for (int j = 0; j < 4; ++j) {
                float s = 0.f;
                #pragma unroll
                for (int k = 0; k < KS; ++k) s = fmaf(wn[k], h[j + k], s);
                accv[q][j] = s;
            }
        }
        const float C1 = 1e-4f, C2 = 9e-4f;
        #pragma unroll
        for (int j = 0; j < 4; ++j) {
            float mp = accv[0][j], mt = accv[1][j];
            float vp = accv[2][j] - mp * mp;
            float vt = accv[3][j] - mt * mt;
            float cv = accv[4][j] - mp * mt;
            float num = (2.f * mp * mt + C1) * (2.f * cv + C2);
            float den = (mp * mp + mt * mt + C1) * (vp + vt + C2);
            lsum = fmaf(num, __builtin_amdgcn_rcpf(den), lsum);
        }
    }

    // ---- Block reduction + one double atomic per block (64 slots) ----
    #pragma unroll
    for (int off = 32; off > 0; off >>= 1)
        lsum += __shfl_down(lsum, off, 64);
    int wave = tid >> 6;
    if ((tid & 63) == 0) red[wave] = lsum;
    __syncthreads();
    if (tid == 0) {
        float bs = red[0] + red[1] + red[2] + red[3];
        int slot = (blockIdx.z * 256 + blockIdx.y * 16 + blockIdx.x) & (NSLOT - 1);
        atomicAdd(&acc[slot], (double)bs);
    }
}

__global__ void ssim_init(double* acc)
{
    if (threadIdx.x < NSLOT) acc[threadIdx.x] = 0.0;
}

__global__ void ssim_fin(const double* __restrict__ acc, float* __restrict__ out,
                         double inv_n)
{
    if (threadIdx.x == 0) {
        double s = 0.0;
        for (int i = 0; i < NSLOT; ++i) s += acc[i];
        out[0] = (float)(1.0 - s * inv_n);
    }
}

extern "C" void kernel_launch(void* const* d_in, const int* in_sizes, int n_in,
                              void* d_out, int out_size, void* d_ws, size_t ws_size,
                              hipStream_t stream)
{
    const float* pred = (const float*)d_in[0];
    const float* targ = (const float*)d_in[1];
    float* out  = (float*)d_out;
    double* acc = (double*)d_ws;

    const long long total = (long long)in_sizes[0];       // 16*3*512*512
    const int n_img = (int)(total / (IMG_H * IMG_W));     // 48 depthwise planes

    hipLaunchKernelGGL(ssim_init, dim3(1), dim3(64), 0, stream, acc);
    dim3 grid(IMG_W / TILE, IMG_H / TILE, n_img);
    hipLaunchKernelGGL(ssim_main, grid, dim3(256), 0, stream, pred, targ, acc);
    hipLaunchKernelGGL(ssim_fin, dim3(1), dim3(1), 0, stream, acc, out,
                       1.0 / (double)total);
}

// Round 3
// 178.722 us; speedup vs baseline: 1.5630x; 1.5630x over previous
//
#include <hip/hip_runtime.h>

#define IMG_H 512
#define IMG_W 512
#define TILE  32
#define RAD   5
#define KS    11
#define SP_H  42            // TILE + 2*RAD halo rows
#define SP_W  46            // 44 used halves, padded (bank shift 23, coprime w/ 32)
#define HT_W  44            // 42 halo rows padded to 44 halves
#define NSLOT 64

typedef _Float16 half2_t __attribute__((ext_vector_type(2)));
typedef _Float16 half4_t __attribute__((ext_vector_type(4)));

__global__ __launch_bounds__(256, 6)
void ssim_main(const float* __restrict__ pred, const float* __restrict__ targ,
               double* __restrict__ acc)
{
    __shared__ _Float16 sp[SP_H][SP_W];
    __shared__ _Float16 st[SP_H][SP_W];
    __shared__ _Float16 hT[5][TILE][HT_W];   // [quantity][out_col][halo_row]
    __shared__ float red[4];

    const float wn[KS] = {0.00102838f, 0.00759876f, 0.03600077f, 0.10936069f,
                          0.21300554f, 0.26601173f, 0.21300554f, 0.10936069f,
                          0.03600077f, 0.00759876f, 0.00102838f};

    const int tid = threadIdx.x;
    const int tx = blockIdx.x, ty = blockIdx.y, img = blockIdx.z;
    const float* __restrict__ p = pred + (size_t)img * (IMG_H * IMG_W);
    const float* __restrict__ t = targ + (size_t)img * (IMG_H * IMG_W);
    const int gr0 = ty * TILE - RAD;          // first halo row (global)
    const int gc0 = tx * TILE;                // first output col (global)
    const int wo  = gc0 - 6;                  // sp col 0 == global col wo (even!)
    const bool colsOK = (tx >= 1) && (tx <= 14);   // cols wo..wo+43 all in-image

    // ---- Phase A: stage halo tile (f32 global -> f16 LDS), zero-pad OOB ----
    // item space: 42 rows x 22 col-pairs = 924; each item handles p AND t
    for (int i = tid; i < SP_H * 22; i += 256) {
        const int r    = i / 22;          // consecutive lanes vary pair -> coalesced
        const int pair = i % 22;
        const int gr   = gr0 + r;
        float2 pv = {0.f, 0.f}, tv = {0.f, 0.f};
        if (gr >= 0 && gr < IMG_H) {
            if (colsOK) {
                const size_t base = (size_t)gr * IMG_W + wo;
                pv = ((const float2*)(p + base))[pair];
                tv = ((const float2*)(t + base))[pair];
            } else {
                int gc = wo + pair * 2;
                if (gc >= 0 && gc < IMG_W)     { pv.x = p[gr*IMG_W+gc];   tv.x = t[gr*IMG_W+gc]; }
                if (gc+1 >= 0 && gc+1 < IMG_W) { pv.y = p[gr*IMG_W+gc+1]; tv.y = t[gr*IMG_W+gc+1]; }
            }
        }
        *(half2_t*)&sp[r][pair*2] = half2_t{(_Float16)pv.x, (_Float16)pv.y};
        *(half2_t*)&st[r][pair*2] = half2_t{(_Float16)tv.x, (_Float16)tv.y};
    }
    __syncthreads();

    // ---- Phase B: horizontal 11-tap pass, 4 outputs/item, store transposed f16 ----
    for (int i = tid; i < SP_H * 8; i += 256) {
        const int r  = i % SP_H;          // consecutive lanes vary r
        const int c0 = (i / SP_H) * 4;
        float pr[16], tr[16];
        #pragma unroll
        for (int v = 0; v < 4; ++v) {
            half4_t hp = *(const half4_t*)&sp[r][c0 + v*4];
            half4_t ht = *(const half4_t*)&st[r][c0 + v*4];
            #pragma unroll
            for (int e = 0; e < 4; ++e) { pr[v*4+e] = (float)hp[e]; tr[v*4+e] = (float)ht[e]; }
        }
        #pragma unroll
        for (int j = 0; j < 4; ++j) {
            float s0 = 0.f, s1 = 0.f, s2 = 0.f, s3 = 0.f, s4 = 0.f;
            #pragma unroll
            for (int k = 0; k < KS; ++k) {
                float pv = pr[j + 1 + k], tv = tr[j + 1 + k];
                float w = wn[k];
                float wp = w * pv, wt = w * tv;
                s0 += wp; s1 += wt;
                s2 = fmaf(wp, pv, s2);
                s3 = fmaf(wt, tv, s3);
                s4 = fmaf(wp, tv, s4);
            }
            hT[0][c0+j][r] = (_Float16)s0;
            hT[1][c0+j][r] = (_Float16)s1;
            hT[2][c0+j][r] = (_Float16)s2;
            hT[3][c0+j][r] = (_Float16)s3;
            hT[4][c0+j][r] = (_Float16)s4;
        }
    }
    __syncthreads();

    // ---- Phase C: vertical 11-tap pass + SSIM ----
    float lsum = 0.f;
    {
        const int c  = tid >> 3;          // output column 0..31
        const int r0 = (tid & 7) * 4;     // output row base 0..28
        float accv[5][4];
        #pragma unroll
        for (int q = 0; q < 5; ++q) {
            float h[16];
            #pragma unroll
            for (int v = 0; v < 4; ++v) {
                half4_t hv = *(const half4_t*)&hT[q][c][r0 + v*4];
                #pragma unroll
                for (int e = 0; e < 4; ++e) h[v*4+e] = (float)hv[e];
            }
            #pragma unroll
            for (int j = 0; j < 4; ++j) {
                float s = 0.f;
                #pragma unroll
                for (int k = 0; k < KS; ++k) s = fmaf(wn[k], h[j + k], s);
                accv[q][j] = s;
            }
        }
        const float C1 = 1e-4f, C2 = 9e-4f;
        #pragma unroll
        for (int j = 0; j < 4; ++j) {
            float mp = accv[0][j], mt = accv[1][j];
            float vp = accv[2][j] - mp * mp;
            float vt = accv[3][j] - mt * mt;
            float cv = accv[4][j] - mp * mt;
            float num = (2.f * mp * mt + C1) * (2.f * cv + C2);
            float den = (mp * mp + mt * mt + C1) * (vp + vt + C2);
            lsum = fmaf(num, __builtin_amdgcn_rcpf(den), lsum);
        }
    }

    // ---- Block reduction + one double atomic per block (64 slots) ----
    #pragma unroll
    for (int off = 32; off > 0; off >>= 1)
        lsum += __shfl_down(lsum, off, 64);
    int wave = tid >> 6;
    if ((tid & 63) == 0) red[wave] = lsum;
    __syncthreads();
    if (tid == 0) {
        float bs = red[0] + red[1] + red[2] + red[3];
        int slot = (blockIdx.z * 256 + blockIdx.y * 16 + blockIdx.x) & (NSLOT - 1);
        atomicAdd(&acc[slot], (double)bs);
    }
}

__global__ void ssim_init(double* acc)
{
    if (threadIdx.x < NSLOT) acc[threadIdx.x] = 0.0;
}

__global__ void ssim_fin(const double* __restrict__ acc, float* __restrict__ out,
                         double inv_n)
{
    if (threadIdx.x == 0) {
        double s = 0.0;
        for (int i = 0; i < NSLOT; ++i) s += acc[i];
        out[0] = (float)(1.0 - s * inv_n);
    }
}

extern "C" void kernel_launch(void* const* d_in, const int* in_sizes, int n_in,
                              void* d_out, int out_size, void* d_ws, size_t ws_size,
                              hipStream_t stream)
{
    const float* pred = (const float*)d_in[0];
    const float* targ = (const float*)d_in[1];
    float* out  = (float*)d_out;
    double* acc = (double*)d_ws;

    const long long total = (long long)in_sizes[0];       // 16*3*512*512
    const int n_img = (int)(total / (IMG_H * IMG_W));     // 48 depthwise planes

    hipLaunchKernelGGL(ssim_init, dim3(1), dim3(64), 0, stream, acc);
    dim3 grid(IMG_W / TILE, IMG_H / TILE, n_img);
    hipLaunchKernelGGL(ssim_main, grid, dim3(256), 0, stream, pred, targ, acc);
    hipLaunchKernelGGL(ssim_fin, dim3(1), dim3(1), 0, stream, acc, out,
                       1.0 / (double)total);
}

// Round 4
// 168.919 us; speedup vs baseline: 1.6537x; 1.0580x over previous
//
#include <hip/hip_runtime.h>
#include <math.h>

#define IMG_H 512
#define IMG_W 512
#define TILE  32
#define RAD   5
#define NSLOT 64

// halo: 42 rows x 48 used cols (pad to stride 52 f16 = 104 B: 8B-aligned rows, 2-way banks)
#define HALO_R 42
#define HALO_S 52
// hT (horizontal sums, transposed [col][row]): 32 cols x 48 used rows, stride 52
#define HT_S   52

typedef _Float16 f16x4 __attribute__((ext_vector_type(4)));
typedef _Float16 f16x8 __attribute__((ext_vector_type(8)));
typedef _Float16 h2    __attribute__((ext_vector_type(2)));
typedef float    f32x4 __attribute__((ext_vector_type(4)));

union F16Frag { f16x8 v8; f16x4 v4[2]; };

__global__ __launch_bounds__(256, 4)
void ssim_main(const float* __restrict__ pred, const float* __restrict__ targ,
               double* __restrict__ acc)
{
    __shared__ _Float16 halo[5][HALO_R][HALO_S];  // p, t, pp, tt, pt
    __shared__ _Float16 hT[5][TILE][HT_S];        // [q][out_col][halo_row]
    __shared__ float wtab[16];
    __shared__ float red[4];

    const int tid  = threadIdx.x;
    const int lane = tid & 63;
    const int wave = tid >> 6;
    const int ln   = lane & 15;     // lane % 16
    const int lg   = lane >> 4;     // lane / 16  (0..3)

    const int tx = blockIdx.x, ty = blockIdx.y, img = blockIdx.z;
    const float* __restrict__ p = pred + (size_t)img * (IMG_H * IMG_W);
    const float* __restrict__ t = targ + (size_t)img * (IMG_H * IMG_W);
    const int gr0 = ty * TILE - RAD;   // halo row 0 (global)
    const int wo  = tx * TILE - 6;     // halo col 0 (global), even for float2 alignment
    // output col n uses halo cols n+1 .. n+11  (band offset -1)

    // ---- weight table (normalized Gaussian sigma=1.5), taps 0..10 ----
    if (tid < 16) {
        float d = (float)tid - 5.0f;
        wtab[tid] = (tid <= 10) ? 0.26601173f * expf(-d * d * 0.22222222f) : 0.0f;
    }
    // ---- zero hT rows 42..47 (read by vertical pass with zero weight; avoid stale NaN) ----
    // items: 5 q x 32 cols x 3 half2-pairs (rows 42/43, 44/45, 46/47) = 480
    for (int i = tid; i < 480; i += 256) {
        int q = i / 96, rem = i % 96;
        int col = rem / 3, pr = rem % 3;
        *(h2*)&hT[q][col][42 + 2 * pr] = h2{(_Float16)0.f, (_Float16)0.f};
    }

    // ---- Stage A: stage 5 halo tiles (f32 global -> f16 LDS), zero-pad OOB ----
    // items: 42 rows x 24 float2-pairs (cols 0..47) = 1008
    const int pairLo = (tx == 0)  ? 3  : 0;
    const int pairHi = (tx == 15) ? 18 : 23;
    for (int i = tid; i < HALO_R * 24; i += 256) {
        const int r = i / 24, pair = i % 24;
        const int gr = gr0 + r;
        float2 pv = {0.f, 0.f}, tv = {0.f, 0.f};
        if (gr >= 0 && gr < IMG_H && pair >= pairLo && pair <= pairHi) {
            const size_t base = (size_t)gr * IMG_W + (wo + 2 * pair);
            pv = *(const float2*)(p + base);
            tv = *(const float2*)(t + base);
        }
        const int c2 = pair * 2;
        *(h2*)&halo[0][r][c2] = h2{(_Float16)pv.x,          (_Float16)pv.y};
        *(h2*)&halo[1][r][c2] = h2{(_Float16)tv.x,          (_Float16)tv.y};
        *(h2*)&halo[2][r][c2] = h2{(_Float16)(pv.x * pv.x), (_Float16)(pv.y * pv.y)};
        *(h2*)&halo[3][r][c2] = h2{(_Float16)(tv.x * tv.x), (_Float16)(tv.y * tv.y)};
        *(h2*)&halo[4][r][c2] = h2{(_Float16)(pv.x * tv.x), (_Float16)(pv.y * tv.y)};
    }
    __syncthreads();

    // ---- Build banded weight fragments (per-lane, from wtab in LDS) ----
    // Horizontal B-frag: B[k][n] = w[k-n-1], k = 8*lg + j, n = ln
    // Vertical   A-frag: A[m][k] = w[k-m],   k = 8*lg + j, m = ln
    f16x8 Bw, A2w;
    #pragma unroll
    for (int j = 0; j < 8; ++j) {
        int k  = lg * 8 + j;
        int dh = k - ln - 1;
        int dv = k - ln;
        float vh = ((unsigned)dh <= 10u) ? wtab[dh & 15] : 0.0f;
        float vv = ((unsigned)dv <= 10u) ? wtab[dv & 15] : 0.0f;
        Bw[j]  = (_Float16)vh;
        A2w[j] = (_Float16)vv;
    }
    const f32x4 zacc = {0.f, 0.f, 0.f, 0.f};

    // ---- Stage B: horizontal conv via MFMA, write transposed f16 ----
    // tiles: rt in {0,1,2} (halo row bases 0,16,26), ct in {0,1} (halo col base 16*ct)
    for (int tt = wave; tt < 6; tt += 4) {
        const int rt = tt >> 1, ct = tt & 1;
        const int rowbase = (rt == 2) ? 26 : rt * 16;
        const int arow = rowbase + ln;
        const int acol = ct * 16 + lg * 8;
        const int ocol = ct * 16 + ln;          // D col
        const int orow = rowbase + lg * 4;      // D row base (4 regs)
        #pragma unroll
        for (int q = 0; q < 5; ++q) {
            F16Frag a;
            a.v4[0] = *(const f16x4*)&halo[q][arow][acol];
            a.v4[1] = *(const f16x4*)&halo[q][arow][acol + 4];
            f32x4 d = __builtin_amdgcn_mfma_f32_16x16x32_f16(a.v8, Bw, zacc, 0, 0, 0);
            *(h2*)&hT[q][ocol][orow]     = h2{(_Float16)d[0], (_Float16)d[1]};
            *(h2*)&hT[q][ocol][orow + 2] = h2{(_Float16)d[2], (_Float16)d[3]};
        }
    }
    __syncthreads();

    // ---- Stage C: vertical conv via MFMA (weights as A), then SSIM ----
    float lsum = 0.f;
    {
        const int ctv = wave & 1, rtv = wave >> 1;   // one 16x16 output tile per wave
        const int ocol  = ctv * 16 + ln;             // B col = output col
        const int rbase = rtv * 16 + lg * 8;         // hT row base for this lane's k-group
        f32x4 accq[5];
        #pragma unroll
        for (int q = 0; q < 5; ++q) {
            F16Frag b;
            b.v4[0] = *(const f16x4*)&hT[q][ocol][rbase];
            b.v4[1] = *(const f16x4*)&hT[q][ocol][rbase + 4];
            accq[q] = __builtin_amdgcn_mfma_f32_16x16x32_f16(A2w, b.v8, zacc, 0, 0, 0);
        }
        const float C1 = 1e-4f, C2 = 9e-4f;
        #pragma unroll
        for (int rgi = 0; rgi < 4; ++rgi) {
            float mp = accq[0][rgi], mt = accq[1][rgi];
            float vp = accq[2][rgi] - mp * mp;
            float vt = accq[3][rgi] - mt * mt;
            float cv = accq[4][rgi] - mp * mt;
            float num = (2.f * mp * mt + C1) * (2.f * cv + C2);
            float den = (mp * mp + mt * mt + C1) * (vp + vt + C2);
            lsum = fmaf(num, __builtin_amdgcn_rcpf(den), lsum);
        }
    }

    // ---- Reduce: wave shuffle -> LDS -> one double atomic per block ----
    #pragma unroll
    for (int off = 32; off > 0; off >>= 1)
        lsum += __shfl_down(lsum, off, 64);
    if ((tid & 63) == 0) red[wave] = lsum;
    __syncthreads();
    if (tid == 0) {
        float bs = red[0] + red[1] + red[2] + red[3];
        int slot = (blockIdx.z * 256 + blockIdx.y * 16 + blockIdx.x) & (NSLOT - 1);
        atomicAdd(&acc[slot], (double)bs);
    }
}

__global__ void ssim_init(double* acc)
{
    if (threadIdx.x < NSLOT) acc[threadIdx.x] = 0.0;
}

__global__ void ssim_fin(const double* __restrict__ acc, float* __restrict__ out,
                         double inv_n)
{
    if (threadIdx.x == 0) {
        double s = 0.0;
        for (int i = 0; i < NSLOT; ++i) s += acc[i];
        out[0] = (float)(1.0 - s * inv_n);
    }
}

extern "C" void kernel_launch(void* const* d_in, const int* in_sizes, int n_in,
                              void* d_out, int out_size, void* d_ws, size_t ws_size,
                              hipStream_t stream)
{
    const float* pred = (const float*)d_in[0];
    const float* targ = (const float*)d_in[1];
    float* out  = (float*)d_out;
    double* acc = (double*)d_ws;

    const long long total = (long long)in_sizes[0];       // 16*3*512*512
    const int n_img = (int)(total / (IMG_H * IMG_W));     // 48 depthwise planes

    hipLaunchKernelGGL(ssim_init, dim3(1), dim3(64), 0, stream, acc);
    dim3 grid(IMG_W / TILE, IMG_H / TILE, n_img);
    hipLaunchKernelGGL(ssim_main, grid, dim3(256), 0, stream, pred, targ, acc);
    hipLaunchKernelGGL(ssim_fin, dim3(1), dim3(1), 0, stream, acc, out,
                       1.0 / (double)total);
}

// Round 5
// 141.404 us; speedup vs baseline: 1.9755x; 1.1946x over previous
//
#include <hip/hip_runtime.h>
#include <math.h>

#define IMG_H 512
#define IMG_W 512
#define TILE  32
#define NSLOT 64

// halo: 42 rows x 48 cols (stride 52 f16 = 104 B; rows 8B-aligned)
#define HALO_R 42
#define HALO_S 52
// hT (horizontal sums, transposed [col][halo_row]): 32 cols x 48 rows, stride 52
#define HT_S   52

typedef _Float16 f16x4 __attribute__((ext_vector_type(4)));
typedef _Float16 f16x8 __attribute__((ext_vector_type(8)));
typedef _Float16 h2    __attribute__((ext_vector_type(2)));
typedef float    f32x4 __attribute__((ext_vector_type(4)));

union F16Frag { f16x8 v8; f16x4 v4[2]; };

__global__ __launch_bounds__(256, 6)
void ssim_main(const float* __restrict__ pred, const float* __restrict__ targ,
               double* __restrict__ acc)
{
    __shared__ _Float16 sAB[2][HALO_R][HALO_S];   // p, t halo tiles only
    __shared__ _Float16 hT[5][TILE][HT_S];        // [q][out_col][halo_row]
    __shared__ float wtab[16];
    __shared__ float red[4];

    const int tid  = threadIdx.x;
    const int lane = tid & 63;
    const int wave = tid >> 6;
    const int ln   = lane & 15;     // lane % 16
    const int lg   = lane >> 4;     // lane / 16  (0..3)

    const int tx = blockIdx.x, ty = blockIdx.y, img = blockIdx.z;
    const float* __restrict__ p = pred + (size_t)img * (IMG_H * IMG_W);
    const float* __restrict__ t = targ + (size_t)img * (IMG_H * IMG_W);
    const int gr0 = ty * TILE - 5;     // halo row 0 (global)
    const int wo  = tx * TILE - 8;     // halo col 0 (global): 16B-aligned
    // output col n uses halo cols n+3 .. n+13  (band offset -3)

    // ---- weight table (normalized Gaussian sigma=1.5), taps 0..10 ----
    if (tid < 16) {
        float d = (float)tid - 5.0f;
        wtab[tid] = (tid <= 10) ? 0.26601173f * expf(-d * d * 0.22222222f) : 0.0f;
    }
    // ---- zero hT rows 42..47 (read by vertical pass with zero weight) ----
    for (int i = tid; i < 480; i += 256) {
        int q = i / 96, rem = i % 96;
        int col = rem / 3, pr = rem % 3;
        *(h2*)&hT[q][col][42 + 2 * pr] = h2{(_Float16)0.f, (_Float16)0.f};
    }

    // ---- Stage A: stage p,t halo (aligned float4 global -> f16x4 LDS) ----
    // 42 rows x 12 float4 col-groups = 504 items; edges are group-aligned:
    // tx==0 -> groups 0,1 fully OOB; tx==15 -> groups 10,11 fully OOB.
    const int gLo = (tx == 0)  ? 2 : 0;
    const int gHi = (tx == 15) ? 9 : 11;
    #pragma unroll
    for (int it = 0; it < 2; ++it) {
        const int i = tid + it * 256;
        if (i < HALO_R * 12) {
            const int r = i / 12, g = i % 12;
            const int gr = gr0 + r;
            float4 pv = {0.f, 0.f, 0.f, 0.f}, tv = {0.f, 0.f, 0.f, 0.f};
            if (gr >= 0 && gr < IMG_H && g >= gLo && g <= gHi) {
                const size_t base = (size_t)gr * IMG_W + (wo + 4 * g);
                pv = *(const float4*)(p + base);
                tv = *(const float4*)(t + base);
            }
            *(f16x4*)&sAB[0][r][4*g] =
                f16x4{(_Float16)pv.x, (_Float16)pv.y, (_Float16)pv.z, (_Float16)pv.w};
            *(f16x4*)&sAB[1][r][4*g] =
                f16x4{(_Float16)tv.x, (_Float16)tv.y, (_Float16)tv.z, (_Float16)tv.w};
        }
    }
    __syncthreads();

    // ---- Banded weight fragments ----
    // Horizontal B-frag: B[k][n] = w[k-n-3], k = 8*lg+j, n = ln
    // Vertical   A-frag: A[m][k] = w[k-m],   k = 8*lg+j, m = ln
    f16x8 Bw, A2w;
    #pragma unroll
    for (int j = 0; j < 8; ++j) {
        int k  = lg * 8 + j;
        int dh = k - ln - 3;
        int dv = k - ln;
        Bw[j]  = (_Float16)(((unsigned)dh <= 10u) ? wtab[dh & 15] : 0.0f);
        A2w[j] = (_Float16)(((unsigned)dv <= 10u) ? wtab[dv & 15] : 0.0f);
    }
    const f32x4 zacc = {0.f, 0.f, 0.f, 0.f};

    // ---- Stage B: horizontal conv via MFMA; form pp/tt/pt on the fly ----
    // tiles: rt in {0,1,2} (halo row bases 0,16,26) x ct in {0,1}
    for (int tt = wave; tt < 6; tt += 4) {
        const int rt = tt >> 1, ct = tt & 1;
        const int rowbase = (rt == 2) ? 26 : rt * 16;
        const int arow = rowbase + ln;
        const int acol = ct * 16 + lg * 8;
        const int ocol = ct * 16 + ln;          // D col
        const int orow = rowbase + lg * 4;      // D row base (4 regs)
        F16Frag pa, ta;
        pa.v4[0] = *(const f16x4*)&sAB[0][arow][acol];
        pa.v4[1] = *(const f16x4*)&sAB[0][arow][acol + 4];
        ta.v4[0] = *(const f16x4*)&sAB[1][arow][acol];
        ta.v4[1] = *(const f16x4*)&sAB[1][arow][acol + 4];
        f16x8 fq[5];
        fq[0] = pa.v8;
        fq[1] = ta.v8;
        fq[2] = pa.v8 * pa.v8;
        fq[3] = ta.v8 * ta.v8;
        fq[4] = pa.v8 * ta.v8;
        #pragma unroll
        for (int q = 0; q < 5; ++q) {
            f32x4 d = __builtin_amdgcn_mfma_f32_16x16x32_f16(fq[q], Bw, zacc, 0, 0, 0);
            *(h2*)&hT[q][ocol][orow]     = h2{(_Float16)d[0], (_Float16)d[1]};
            *(h2*)&hT[q][ocol][orow + 2] = h2{(_Float16)d[2], (_Float16)d[3]};
        }
    }
    __syncthreads();

    // ---- Stage C: vertical conv via MFMA (weights as A), then SSIM ----
    float lsum = 0.f;
    {
        const int ctv = wave & 1, rtv = wave >> 1;   // one 16x16 output tile per wave
        const int ocol  = ctv * 16 + ln;             // B col = output col
        const int rbase = rtv * 16 + lg * 8;         // hT row base for this lane's k-group
        f32x4 accq[5];
        #pragma unroll
        for (int q = 0; q < 5; ++q) {
            F16Frag b;
            b.v4[0] = *(const f16x4*)&hT[q][ocol][rbase];
            b.v4[1] = *(const f16x4*)&hT[q][ocol][rbase + 4];
            accq[q] = __builtin_amdgcn_mfma_f32_16x16x32_f16(A2w, b.v8, zacc, 0, 0, 0);
        }
        const float C1 = 1e-4f, C2 = 9e-4f;
        #pragma unroll
        for (int rgi = 0; rgi < 4; ++rgi) {
            float mp = accq[0][rgi], mt = accq[1][rgi];
            float vp = accq[2][rgi] - mp * mp;
            float vt = accq[3][rgi] - mt * mt;
            float cv = accq[4][rgi] - mp * mt;
            float num = (2.f * mp * mt + C1) * (2.f * cv + C2);
            float den = (mp * mp + mt * mt + C1) * (vp + vt + C2);
            lsum = fmaf(num, __builtin_amdgcn_rcpf(den), lsum);
        }
    }

    // ---- Reduce: wave shuffle -> LDS -> one double atomic per block ----
    #pragma unroll
    for (int off = 32; off > 0; off >>= 1)
        lsum += __shfl_down(lsum, off, 64);
    if ((tid & 63) == 0) red[wave] = lsum;
    __syncthreads();
    if (tid == 0) {
        float bs = red[0] + red[1] + red[2] + red[3];
        int slot = (blockIdx.z * 256 + blockIdx.y * 16 + blockIdx.x) & (NSLOT - 1);
        atomicAdd(&acc[slot], (double)bs);
    }
}

__global__ void ssim_init(double* acc)
{
    if (threadIdx.x < NSLOT) acc[threadIdx.x] = 0.0;
}

__global__ void ssim_fin(const double* __restrict__ acc, float* __restrict__ out,
                         double inv_n)
{
    if (threadIdx.x == 0) {
        double s = 0.0;
        for (int i = 0; i < NSLOT; ++i) s += acc[i];
        out[0] = (float)(1.0 - s * inv_n);
    }
}

extern "C" void kernel_launch(void* const* d_in, const int* in_sizes, int n_in,
                              void* d_out, int out_size, void* d_ws, size_t ws_size,
                              hipStream_t stream)
{
    const float* pred = (const float*)d_in[0];
    const float* targ = (const float*)d_in[1];
    float* out  = (float*)d_out;
    double* acc = (double*)d_ws;

    const long long total = (long long)in_sizes[0];       // 16*3*512*512
    const int n_img = (int)(total / (IMG_H * IMG_W));     // 48 depthwise planes

    hipLaunchKernelGGL(ssim_init, dim3(1), dim3(64), 0, stream, acc);
    dim3 grid(IMG_W / TILE, IMG_H / TILE, n_img);
    hipLaunchKernelGGL(ssim_main, grid, dim3(256), 0, stream, pred, targ, acc);
    hipLaunchKernelGGL(ssim_fin, dim3(1), dim3(1), 0, stream, acc, out,
                       1.0 / (double)total);
}